// Round 5
// baseline (788.510 us; speedup 1.0000x reference)
//
#include <hip/hip_runtime.h>
#include <hip/hip_bf16.h>

#define N_ATOMS 100000
#define N_RES   12500
#define N_EDGES 800000
#define D_IN    37
#define D       115
#define DP      128            // padded feature dim (bf16 row = 256 B)
#define MPAD    100096         // atoms padded to multiple of 128
#define N_LAYERS 4
#define SCE     1024           // elements per scan block (256 thr x 4)
#define NSCB    ((N_ATOMS + SCE - 1) / SCE)   // 98 scan blocks
#define KPROJ   64             // D_IN padded to MFMA K multiple
#define LSTRIDE 72             // proj LDS row stride (bf16)
#define LSTR2   136            // layer LDS row stride (bf16): 272 B -> bank step 4, 2-way free

typedef __bf16 bf16x8 __attribute__((ext_vector_type(8)));
typedef float  f32x4  __attribute__((ext_vector_type(4)));
typedef unsigned int u32x4 __attribute__((ext_vector_type(4)));

__device__ __forceinline__ unsigned short f2bf(float f) {
  unsigned u = __builtin_bit_cast(unsigned, f);
  u += 0x7fffu + ((u >> 16) & 1u);            // RNE
  return (unsigned short)(u >> 16);
}
__device__ __forceinline__ float bf2f(unsigned short h) {
  unsigned u = ((unsigned)h) << 16;
  return __builtin_bit_cast(float, u);
}
__device__ __forceinline__ bf16x8 ld_frag(const unsigned short* p) {
  u32x4 u = *reinterpret_cast<const u32x4*>(p);
  return __builtin_bit_cast(bf16x8, u);
}

// ---- CSR build -------------------------------------------------------------
__global__ void k_hist_edges(const int* __restrict__ eidx, int* __restrict__ hist) {
  int e = blockIdx.x * blockDim.x + threadIdx.x;
  if (e < N_EDGES) atomicAdd(&hist[eidx[N_EDGES + e]], 1);
}

// 3-phase device-wide exclusive scan over N_ATOMS counts
__global__ __launch_bounds__(256) void k_scan_part(
    const int* __restrict__ cnt, int* __restrict__ bsum)
{
  __shared__ int sh[256];
  const int t = threadIdx.x, b = blockIdx.x;
  const int base = b * SCE + t * 4;
  int s = 0;
  #pragma unroll
  for (int i = 0; i < 4; ++i) { int id = base + i; if (id < N_ATOMS) s += cnt[id]; }
  sh[t] = s; __syncthreads();
  for (int d = 128; d > 0; d >>= 1) { if (t < d) sh[t] += sh[t + d]; __syncthreads(); }
  if (t == 0) bsum[b] = sh[0];
}
__global__ __launch_bounds__(256) void k_scan_bsum(
    int* __restrict__ bsum, int* __restrict__ total)
{
  __shared__ int sh[256];
  const int t = threadIdx.x;
  int v = (t < NSCB) ? bsum[t] : 0;
  sh[t] = v; __syncthreads();
  for (int d = 1; d < 256; d <<= 1) {
    int u = (t >= d) ? sh[t - d] : 0;
    __syncthreads();
    sh[t] += u;
    __syncthreads();
  }
  if (t < NSCB) bsum[t] = sh[t] - v;          // exclusive
  if (t == 255) *total = sh[255];             // offs[N_ATOMS]
}
__global__ __launch_bounds__(256) void k_scan_final(
    const int* __restrict__ cnt, const int* __restrict__ bsum,
    int* __restrict__ offs, int* __restrict__ cursor, float* __restrict__ invdeg)
{
  __shared__ int sh[256];
  const int t = threadIdx.x, b = blockIdx.x;
  const int base = b * SCE + t * 4;
  int c[4]; int s = 0;
  #pragma unroll
  for (int i = 0; i < 4; ++i) {
    int id = base + i;
    c[i] = (id < N_ATOMS) ? cnt[id] : 0;
    s += c[i];
  }
  sh[t] = s; __syncthreads();
  for (int d = 1; d < 256; d <<= 1) {
    int u = (t >= d) ? sh[t - d] : 0;
    __syncthreads();
    sh[t] += u;
    __syncthreads();
  }
  int run = bsum[b] + sh[t] - s;              // exclusive prefix for this thread
  #pragma unroll
  for (int i = 0; i < 4; ++i) {
    int id = base + i;
    if (id < N_ATOMS) {
      offs[id] = run;
      cursor[id] = run;
      invdeg[id] = 1.0f / (float)max(c[i], 1);
      run += c[i];
    }
  }
}

// residue CSR via binary search (r2a is sorted): res_start[r] = lower_bound(r)
__global__ __launch_bounds__(256) void k_res_bounds(
    const int* __restrict__ r2a, int* __restrict__ res_start)
{
  int r = blockIdx.x * blockDim.x + threadIdx.x;
  if (r > N_RES) return;
  int lo = 0, hi = N_ATOMS;
  while (lo < hi) {
    int mid = (lo + hi) >> 1;
    if (r2a[mid] < r) lo = mid + 1; else hi = mid;
  }
  res_start[r] = lo;
}

__global__ void k_fill(const int* __restrict__ eidx, int* __restrict__ cursor,
                       int* __restrict__ srcs) {
  int e = blockIdx.x * blockDim.x + threadIdx.x;
  if (e < N_EDGES) {
    int s = eidx[e], d = eidx[N_EDGES + e];
    int pos = atomicAdd(&cursor[d], 1);
    srcs[pos] = s;
  }
}

// ---- weight pad/convert: W[115][115] f32 -> [128][128] bf16 (c-major) ------
__global__ void k_convw(const float* __restrict__ Wl, const float* __restrict__ Wr,
                        unsigned short* __restrict__ wpad)
{
  const int k = threadIdx.x;   // 0..127
  const int c = blockIdx.x;    // 0..127
  const int m = blockIdx.y;    // 0..7  (0-3 = Wl layers, 4-7 = Wr layers)
  const float* src = (m < 4) ? (Wl + m * D * D) : (Wr + (m - 4) * D * D);
  unsigned short v = 0;
  if (c < D && k < D) v = f2bf(src[c * D + k]);
  wpad[(m * 128 + c) * 128 + k] = v;
}

// ---- input projection via MFMA: x0 = A @ lnW^T + lnb, bf16 [MPAD][128] -----
__global__ __launch_bounds__(256) void k_proj(
    const float* __restrict__ A, const float* __restrict__ Wf,
    const float* __restrict__ bf, unsigned short* __restrict__ xout)
{
  __shared__ unsigned short sA[128 * LSTRIDE];
  __shared__ unsigned short sW[128 * LSTRIDE];
  const int t = threadIdx.x;
  const int r0 = blockIdx.x * 128;

  for (int idx = t; idx < 128 * KPROJ; idx += 256) {
    const int row = idx >> 6, k = idx & 63;
    const int gr = r0 + row;
    unsigned short v = 0;
    if (k < D_IN && gr < N_ATOMS) v = f2bf(A[(size_t)gr * D_IN + k]);
    sA[row * LSTRIDE + k] = v;
  }
  for (int idx = t; idx < 128 * KPROJ; idx += 256) {
    const int col = idx >> 6, k = idx & 63;
    unsigned short v = 0;
    if (col < D && k < D_IN) v = f2bf(Wf[col * D_IN + k]);
    sW[col * LSTRIDE + k] = v;
  }
  __syncthreads();

  const int lane = t & 63;
  const int wid  = t >> 6;
  const int wrow = wid * 32;
  const int lrow = lane & 15;
  const int koff = (lane >> 4) * 8;

  f32x4 acc[2][8];
  #pragma unroll
  for (int i = 0; i < 2; ++i)
    #pragma unroll
    for (int j = 0; j < 8; ++j)
      acc[i][j] = (f32x4){0.f, 0.f, 0.f, 0.f};

  #pragma unroll
  for (int ks = 0; ks < 2; ++ks) {
    const int k0 = ks * 32 + koff;
    bf16x8 a0 = ld_frag(&sA[(wrow + lrow) * LSTRIDE + k0]);
    bf16x8 a1 = ld_frag(&sA[(wrow + 16 + lrow) * LSTRIDE + k0]);
    #pragma unroll
    for (int ct = 0; ct < 8; ++ct) {
      bf16x8 b = ld_frag(&sW[(ct * 16 + lrow) * LSTRIDE + k0]);
      acc[0][ct] = __builtin_amdgcn_mfma_f32_16x16x32_bf16(a0, b, acc[0][ct], 0, 0, 0);
      acc[1][ct] = __builtin_amdgcn_mfma_f32_16x16x32_bf16(a1, b, acc[1][ct], 0, 0, 0);
    }
  }

  const int ocol = lane & 15;
  const int orow = (lane >> 4) * 4;
  #pragma unroll
  for (int ct = 0; ct < 8; ++ct) {
    const int col = ct * 16 + ocol;
    const float bv = (col < D) ? bf[col] : 0.f;
    #pragma unroll
    for (int rt = 0; rt < 2; ++rt) {
      #pragma unroll
      for (int j = 0; j < 4; ++j) {
        const int grow = r0 + wrow + rt * 16 + orow + j;
        if (grow < N_ATOMS)
          xout[(size_t)grow * DP + col] = f2bf(acc[rt][ct][j] + bv);
      }
    }
  }
}

// ---- fused layer: gather-mean into LDS, then MFMA --------------------------
// Phase 1: 16 quarter-waves/block, one row each x8: 16 lanes x 16 B dwordx4
// gathers (4x fewer load instrs than 4 B/lane), edge-index batches of 16 for ILP.
// Phase 2: xout = agg @ Wl^T + xin @ Wr^T + bl; agg A-frags from LDS
// (stride 136 bf16 -> bank step 4 -> 2-way aliasing, free), xin streamed global.
__global__ __launch_bounds__(256) void k_layer(
    const unsigned short* __restrict__ xin,
    const int* __restrict__ row_start,
    const int* __restrict__ srcs,
    const float* __restrict__ invdeg,
    const unsigned short* __restrict__ wl,   // [128][128] bf16, c-major
    const unsigned short* __restrict__ wr,
    const float* __restrict__ bias,          // 115 floats
    unsigned short* __restrict__ xout)
{
  __shared__ unsigned short sAgg[128 * LSTR2];   // 34.8 KB
  const int t = threadIdx.x;
  const int r0 = blockIdx.x * 128;
  const int rp = t >> 4;          // row processor 0..15
  const int ql = t & 15;          // lane within quarter

  // ---- phase 1: gather-mean the block's 128 rows into LDS ----
  for (int i = 0; i < 8; ++i) {
    const int row = rp * 8 + i;
    const int grow = r0 + row;
    float a[8] = {0.f,0.f,0.f,0.f,0.f,0.f,0.f,0.f};
    float sc = 0.f;
    if (grow < N_ATOMS) {
      const int beg = row_start[grow], end = row_start[grow + 1];
      sc = invdeg[grow];
      for (int b2 = beg; b2 < end; b2 += 16) {
        const int m = end - b2;
        int sidx = 0;
        if (ql < m) sidx = srcs[b2 + ql];
        #pragma unroll
        for (int j = 0; j < 16; ++j) {
          if (j < m) {
            const int s = __shfl(sidx, (t & 48) + j);   // quarter's lane j
            const u32x4 v = *(reinterpret_cast<const u32x4*>(xin + (size_t)s * DP) + ql);
            #pragma unroll
            for (int q = 0; q < 4; ++q) {
              a[2*q]   += bf2f((unsigned short)(v[q] & 0xffffu));
              a[2*q+1] += bf2f((unsigned short)(v[q] >> 16));
            }
          }
        }
      }
    }
    unsigned int w[4];
    #pragma unroll
    for (int q = 0; q < 4; ++q)
      w[q] = (unsigned int)f2bf(a[2*q] * sc) | ((unsigned int)f2bf(a[2*q+1] * sc) << 16);
    *reinterpret_cast<u32x4*>(&sAgg[row * LSTR2 + ql * 8]) = (u32x4){w[0], w[1], w[2], w[3]};
  }
  __syncthreads();

  // ---- phase 2: MFMA ----
  const int lane = t & 63;
  const int wid  = t >> 6;
  const int wrow = wid * 32;
  const int lrow = lane & 15;
  const int koff = (lane >> 4) * 8;

  f32x4 acc[2][8];
  #pragma unroll
  for (int i = 0; i < 2; ++i)
    #pragma unroll
    for (int j = 0; j < 8; ++j)
      acc[i][j] = (f32x4){0.f, 0.f, 0.f, 0.f};

  // agg (LDS) @ Wl^T
  #pragma unroll
  for (int ks = 0; ks < 4; ++ks) {
    const int k0 = ks * 32 + koff;
    bf16x8 a0 = ld_frag(&sAgg[(wrow + lrow) * LSTR2 + k0]);
    bf16x8 a1 = ld_frag(&sAgg[(wrow + 16 + lrow) * LSTR2 + k0]);
    #pragma unroll
    for (int ct = 0; ct < 8; ++ct) {
      bf16x8 b = ld_frag(&wl[(ct * 16 + lrow) * DP + k0]);
      acc[0][ct] = __builtin_amdgcn_mfma_f32_16x16x32_bf16(a0, b, acc[0][ct], 0, 0, 0);
      acc[1][ct] = __builtin_amdgcn_mfma_f32_16x16x32_bf16(a1, b, acc[1][ct], 0, 0, 0);
    }
  }
  // xin (global) @ Wr^T   (rows >= N_ATOMS read garbage; their C rows unwritten)
  #pragma unroll
  for (int ks = 0; ks < 4; ++ks) {
    const int k0 = ks * 32 + koff;
    bf16x8 a0 = ld_frag(&xin[(size_t)(r0 + wrow + lrow) * DP + k0]);
    bf16x8 a1 = ld_frag(&xin[(size_t)(r0 + wrow + 16 + lrow) * DP + k0]);
    #pragma unroll
    for (int ct = 0; ct < 8; ++ct) {
      bf16x8 b = ld_frag(&wr[(ct * 16 + lrow) * DP + k0]);
      acc[0][ct] = __builtin_amdgcn_mfma_f32_16x16x32_bf16(a0, b, acc[0][ct], 0, 0, 0);
      acc[1][ct] = __builtin_amdgcn_mfma_f32_16x16x32_bf16(a1, b, acc[1][ct], 0, 0, 0);
    }
  }

  const int ocol = lane & 15;
  const int orow = (lane >> 4) * 4;   // C/D: col=lane&15, row=(lane>>4)*4+reg
  #pragma unroll
  for (int ct = 0; ct < 8; ++ct) {
    const int col = ct * 16 + ocol;
    const float bv = (col < D) ? bias[col] : 0.f;
    #pragma unroll
    for (int rt = 0; rt < 2; ++rt) {
      #pragma unroll
      for (int j = 0; j < 4; ++j) {
        const int grow = r0 + wrow + rt * 16 + orow + j;
        if (grow < N_ATOMS)
          xout[(size_t)grow * DP + col] = f2bf(acc[rt][ct][j] + bv);
      }
    }
  }
}

// ---- residue pooling: sorted segment-sum, one wave per residue -------------
__global__ __launch_bounds__(256) void k_pool(
    const unsigned int* __restrict__ x, const int* __restrict__ res_start,
    float* __restrict__ out)
{
  const int r = (int)((blockIdx.x * 256 + threadIdx.x) >> 6);
  const int lane = threadIdx.x & 63;
  if (r >= N_RES) return;
  const int beg = res_start[r], end = res_start[r + 1];
  float a0 = 0.f, a1 = 0.f;
  for (int a = beg; a < end; ++a) {
    unsigned int v = x[a * 64 + lane];
    a0 += bf2f((unsigned short)(v & 0xffffu));
    a1 += bf2f((unsigned short)(v >> 16));
  }
  const int c0 = lane * 2;
  if (c0 < D)     out[(size_t)r * D + c0]     = a0;
  if (c0 + 1 < D) out[(size_t)r * D + c0 + 1] = a1;
}

extern "C" void kernel_launch(void* const* d_in, const int* in_sizes, int n_in,
                              void* d_out, int out_size, void* d_ws, size_t ws_size,
                              hipStream_t stream)
{
  (void)in_sizes; (void)n_in; (void)out_size; (void)ws_size;
  const float* atom_emb = (const float*)d_in[1];
  const int*   eidx     = (const int*)d_in[2];
  const int*   r2a      = (const int*)d_in[3];
  const float* lnW      = (const float*)d_in[4];
  const float* lnb      = (const float*)d_in[5];
  const float* Wl       = (const float*)d_in[6];
  const float* Wr       = (const float*)d_in[7];
  const float* bl       = (const float*)d_in[8];
  float* out = (float*)d_out;

  char* p = (char*)d_ws;
  auto alloc = [&](size_t b) { char* r = p; p += (b + 255) & ~(size_t)255; return r; };
  unsigned short* xb0  = (unsigned short*)alloc((size_t)MPAD * DP * 2);
  unsigned short* xb1  = (unsigned short*)alloc((size_t)MPAD * DP * 2);
  unsigned short* wpad = (unsigned short*)alloc((size_t)8 * 128 * 128 * 2);
  int*   hist      = (int*)alloc((size_t)N_ATOMS * 4);
  int*   row_start = (int*)alloc((size_t)(N_ATOMS + 1) * 4);
  int*   cursor    = (int*)alloc((size_t)N_ATOMS * 4);
  float* invdeg    = (float*)alloc((size_t)N_ATOMS * 4);
  int*   srcs      = (int*)alloc((size_t)N_EDGES * 4);
  int*   bsum      = (int*)alloc((size_t)256 * 4);
  int*   res_start = (int*)alloc((size_t)(N_RES + 1) * 4);

  hipMemsetAsync(hist, 0, (size_t)N_ATOMS * 4, stream);

  k_convw<<<dim3(128, 8), 128, 0, stream>>>(Wl, Wr, wpad);
  k_hist_edges<<<(N_EDGES + 255) / 256, 256, 0, stream>>>(eidx, hist);
  k_scan_part<<<NSCB, 256, 0, stream>>>(hist, bsum);
  k_scan_bsum<<<1, 256, 0, stream>>>(bsum, row_start + N_ATOMS);
  k_scan_final<<<NSCB, 256, 0, stream>>>(hist, bsum, row_start, cursor, invdeg);
  k_res_bounds<<<(N_RES + 1 + 255) / 256, 256, 0, stream>>>(r2a, res_start);
  k_fill<<<(N_EDGES + 255) / 256, 256, 0, stream>>>(eidx, cursor, srcs);
  k_proj<<<MPAD / 128, 256, 0, stream>>>(atom_emb, lnW, lnb, xb0);

  unsigned short* cur = xb0;
  unsigned short* nxt = xb1;
  for (int l = 0; l < N_LAYERS; ++l) {
    k_layer<<<MPAD / 128, 256, 0, stream>>>(
        cur, row_start, srcs, invdeg,
        wpad + (size_t)l * 16384, wpad + (size_t)(4 + l) * 16384,
        bl + (size_t)l * D, nxt);
    unsigned short* tmp = cur; cur = nxt; nxt = tmp;
  }
  k_pool<<<(N_RES * 64) / 256, 256, 0, stream>>>(
      (const unsigned int*)cur, res_start, out);
}